// Round 1
// baseline (654.216 us; speedup 1.0000x reference)
//
#include <hip/hip_runtime.h>
#include <hip/hip_bf16.h>
#include <math.h>

#define NLAT_I 240
#define NLON_I 480
#define NLAT_O 361
#define NLON_O 720
#define CI_N 32
#define CO_N 32
#define K_N 7
#define WOFF 10
#define WLAT 21

#define PI_F 3.14159265358979323846f
#define TWOPI_F 6.28318530717958647692f
#define DLAT_V (PI_F / 360.0f)
#define DPHI_V (TWOPI_F / 720.0f)
#define CUTOFF_V (3.25f * PI_F / 120.0f)
#define DR_V (CUTOFF_V / 3.0f)
#define IDR_V (1.0f / DR_V)
#define DPH_V (TWOPI_F / 3.0f)
#define IDPH_V (1.0f / DPH_V)
#define QF_V (DLAT_V * DPHI_V)

#define PAD_T 64        // Toeplitz pad (covers fragment reach beyond support)
#define CT 64           // positions (units) per work item
#define NBLK 256        // 1 block/CU (8 waves, 2/SIMD: reg-limited)
#define NTHR 512
#define NC45 45         // 720/16 column chunks
#define NE 7581         // 361*21

typedef __attribute__((ext_vector_type(8))) short short8v;
typedef __attribute__((ext_vector_type(4))) short short4v;
typedef __attribute__((ext_vector_type(16))) float f32x16;
typedef __attribute__((ext_vector_type(4))) float f32x4;

__device__ __forceinline__ unsigned short f2bf(float f) {
  __hip_bfloat16 h = __float2bfloat16(f);   // RTNE
  union { __hip_bfloat16 b; unsigned short s; } u; u.b = h; return u.s;
}

// ---------------- psi evaluation --------------------------------------------
__device__ __forceinline__ void psi_eval(float ct, float st, float cg, float sg,
                                         float q, float bang, float v[7]) {
  float sb, cb;
  sincosf(bang, &sb, &cb);
  float dx = sg * cb - st;
  float dy = sg * sb;
  float dz = cg - ct;
  float c2 = dx * dx + dy * dy + dz * dz;
  float r = 2.0f * asinf(fminf(1.0f, 0.5f * sqrtf(c2)));
  if (r <= CUTOFF_V) {
    float xx = ct * cb * sg - st * cg;
    float yy = sb * sg;
    float phi = atan2f(yy, xx);
    if (phi < 0.0f) phi += TWOPI_F;
    v[0] = fmaxf(0.0f, 1.0f - r * IDR_V) * q;
#pragma unroll
    for (int k = 1; k < 7; ++k) {
      const float irdr = (float)(1 + (k - 1) / 3) * DR_V;
      const float ipph = (float)((k - 1) % 3) * DPH_V;
      float rad = fmaxf(0.0f, 1.0f - fabsf(r - irdr) * IDR_V);
      float dd = fabsf(phi - ipph);
      dd = fminf(dd, TWOPI_F - dd);
      float az = fmaxf(0.0f, 1.0f - dd * IDPH_V);
      v[k] = rad * az * q;
    }
  } else {
#pragma unroll
    for (int k = 0; k < 7; ++k) v[k] = 0.0f;
  }
}

// per-(t,d) lon window half-width: -1 empty, 360 full circle
__device__ __forceinline__ int windowB(int t, int d) {
  int tp = t + d - WOFF;
  if (tp < 0 || tp > NLAT_O - 1) return -1;
  float th = (float)t * DLAT_V, ga = (float)tp * DLAT_V;
  float st = sinf(th), ct = cosf(th), sg = sinf(ga), cg = cosf(ga);
  float den = st * sg;
  float num = cosf(CUTOFF_V) - ct * cg;
  if (den < 1e-9f) return (fabsf(th - ga) <= CUTOFF_V) ? 360 : -1;
  if (num >= den) return -1;
  if (num <= -den) return 360;
  int B = (int)ceilf(acosf(num / den) * (1.0f / DPHI_V)) + 1;  // +1 margin; psi masks
  return B > 360 ? 360 : B;
}

__device__ __forceinline__ int nsupOf(int B) { return (B >= 360) ? 720 : 2 * B + 1; }
__device__ __forceinline__ int widthOf(int B) {
  return (B < 0) ? 0 : ((nsupOf(B) + 129) & ~1);   // even
}

// ---------------- kernel 0: prep (w2, scans, wtab, sums=0, counter) ---------
__global__ void prep_kernel(const float* __restrict__ w, unsigned short* __restrict__ w2,
                            int* __restrict__ offsF, int* __restrict__ offsT,
                            int* __restrict__ wtab, float* __restrict__ sums,
                            int* __restrict__ counter) {
  const int tid = threadIdx.x;
  __shared__ int temp[256];
  if (tid == 0) *counter = 0;
  for (int idx = tid; idx < 361 * 7; idx += 256) sums[idx] = 0.0f;
  // w2[c16][o][kk] = bf16(w[o][i][k]) with ci=c16*16+kk, k=ci>>5, i=ci&31
  for (int idx = tid; idx < 14 * 32 * 16; idx += 256) {
    int kk = idx & 15; int o = (idx >> 4) & 31; int c16 = idx >> 9;
    int ci = c16 * 16 + kk; int i = ci & 31; int k = ci >> 5;
    w2[idx] = f2bf(w[(o * 32 + i) * 7 + k]);
  }
  for (int e = tid; e < NE; e += 256) {
    int t = e / 21, d = e % 21;
    int B = windowB(t, d);
    offsF[e] = (B >= 0) ? nsupOf(B) * 7 : 0;
    offsT[e] = 14 * widthOf(B);
  }
  for (int t = tid; t < 361; t += 256) {
    int Wt = 0;
    for (int d = 0; d < WLAT; ++d) {
      int B = windowB(t, d);
      if (B >= 0) Wt += ((31 + B) >> 4) + ((B + 15) >> 4) + 1;
    }
    wtab[t] = Wt;
  }
  __syncthreads();
  // two-level exclusive scan for offsF then offsT (chunk = 30, 256*30 >= NE)
#pragma unroll 1
  for (int pass = 0; pass < 2; ++pass) {
    int* a = pass ? offsT : offsF;
    int s = tid * 30, e = s + 30; if (e > NE) e = NE; if (s > NE) s = NE;
    int sum = 0;
    for (int i = s; i < e; ++i) sum += a[i];
    temp[tid] = sum;
    __syncthreads();
    if (tid == 0) {
      int run = 0;
      for (int i = 0; i < 256; ++i) { int v = temp[i]; temp[i] = run; run += v; }
      a[NE] = run;
    }
    __syncthreads();
    int run = temp[tid];
    for (int i = s; i < e; ++i) { int v = a[i]; a[i] = run; run += v; }
    __syncthreads();
  }
}

// ---------------- kernel 1: bilinear upsample -> tiled bf16 XT --------------
// XT[t][c][i][kk] with b = c*16+kk  (wave A-load = contiguous 1KB)
__global__ void upsample_kernel(const float* __restrict__ x,
                                unsigned short* __restrict__ XT) {
  int idx = blockIdx.x * 256 + threadIdx.x;
  if (idx >= NLAT_O * NC45 * 512) return;
  int kk = idx & 15;
  int i = (idx >> 4) & 31;
  int c = (idx >> 9) % NC45;
  int t = idx / (NC45 * 512);
  int p = c * 16 + kk;

  double post = (double)t * (239.0 / 360.0);
  int i0 = (int)floor(post);
  if (i0 < 0) i0 = 0;
  if (i0 > NLAT_I - 1) i0 = NLAT_I - 1;
  int i1 = i0 + 1; if (i1 > NLAT_I - 1) i1 = NLAT_I - 1;
  float wt = (float)(post - (double)i0);

  double posp = (double)p * (2.0 / 3.0);
  double j0f = floor(posp);
  int j0 = ((int)j0f) % NLON_I;
  int j1 = (j0 + 1) % NLON_I;
  float wp = (float)(posp - j0f);

  const float* xi = x + (size_t)i * (NLAT_I * NLON_I);
  float a = xi[i0 * NLON_I + j0];
  float b = xi[i0 * NLON_I + j1];
  float cc = xi[i1 * NLON_I + j0];
  float d = xi[i1 * NLON_I + j1];
  float l0 = (1.0f - wt) * a + wt * cc;
  float l1 = (1.0f - wt) * b + wt * d;
  XT[idx] = f2bf((1.0f - wp) * l0 + wp * l1);
}

// ---------------- kernel 2: raw psi (f32) + fused per-(k,t) partial sums ----
__global__ void psi_raw_kernel(const int* __restrict__ offsF,
                               float* __restrict__ PSIF,
                               float* __restrict__ sums) {
  int t = blockIdx.x, d = blockIdx.y;
  int B = windowB(t, d);
  if (B < 0) return;
  int nsup = nsupOf(B);
  int bLo = (B >= 360) ? -360 : -B;
  int offF = offsF[t * 21 + d];
  int tp = t + d - WOFF;
  float th = (float)t * DLAT_V, ga = (float)tp * DLAT_V;
  float st, ct, sg, cg;
  sincosf(th, &st, &ct);
  sincosf(ga, &sg, &cg);
  float q = sg * QF_V;
  float acc[7];
#pragma unroll
  for (int k = 0; k < 7; ++k) acc[k] = 0.0f;
  for (int ix = threadIdx.x; ix < nsup; ix += 256) {
    float v[7];
    psi_eval(ct, st, cg, sg, q, (float)(bLo + ix) * DPHI_V, v);
#pragma unroll
    for (int k = 0; k < 7; ++k) { PSIF[offF + k * nsup + ix] = v[k]; acc[k] += v[k]; }
  }
#pragma unroll
  for (int k = 0; k < 7; ++k) {
    float a = acc[k];
    for (int off = 32; off > 0; off >>= 1) a += __shfl_down(a, off, 64);
    acc[k] = a;
  }
  __shared__ float red[4][7];
  int wid = threadIdx.x >> 6;
  if ((threadIdx.x & 63) == 0) {
#pragma unroll
    for (int k = 0; k < 7; ++k) red[wid][k] = acc[k];
  }
  __syncthreads();
  if (threadIdx.x == 0) {
#pragma unroll
    for (int k = 0; k < 7; ++k)
      atomicAdd(&sums[t * 7 + k], red[0][k] + red[1][k] + red[2][k] + red[3][k]);
  }
}

// ---------------- kernel 3: normalized bf16 Toeplitz (2 parity copies) ------
__global__ void psi_toep_kernel(const int* __restrict__ offsF,
                                const int* __restrict__ offsT,
                                const float* __restrict__ PSIF,
                                const float* __restrict__ sums,
                                unsigned short* __restrict__ PSIT) {
  int t = blockIdx.x, d = blockIdx.y;
  int B = windowB(t, d);
  if (B < 0) return;
  int nsup = nsupOf(B);
  int width = widthOf(B);
  int offF = offsF[t * 21 + d];
  int offT = offsT[t * 21 + d];
  float rc[7];
#pragma unroll
  for (int k = 0; k < 7; ++k) rc[k] = 1.0f / fmaxf(sums[t * 7 + k], 1e-8f);
  for (int ix = threadIdx.x; ix <= width; ix += 256) {
    int isup = ix - PAD_T;
    unsigned short vv[7];
    if (isup >= 0 && isup < nsup) {
#pragma unroll
      for (int k = 0; k < 7; ++k)
        vv[k] = f2bf(PSIF[offF + k * nsup + isup] * rc[k]);
    } else {
#pragma unroll
      for (int k = 0; k < 7; ++k) vv[k] = 0;
    }
    if (ix < width) {
#pragma unroll
      for (int k = 0; k < 7; ++k) PSIT[offT + (2 * k) * width + ix] = vv[k];
    }
    if (ix >= 1) {
#pragma unroll
      for (int k = 0; k < 7; ++k) PSIT[offT + (2 * k + 1) * width + ix - 1] = vv[k];
    }
  }
}

// ---------------- kernel 4: persistent MFMA conv, 8-wave k-split ------------
// Waves 0-3: ptiles 0-3 of the pgroup, k-bases 0..3.  Waves 4-7: same ptiles,
// k-bases 4..6.  Halved accumulator (64 AGPR) funds a depth-4 prefetch ring;
// flat per-unit metadata (LDS) + readfirstlane scalarization keep the ring
// running across d-run boundaries with minimal VALU.

#define LOADK(S, MI, K4) {                                                    \
    int mi_ = (MI); if (mi_ >= nU) mi_ = nU - 1;                              \
    int mx_ = __builtin_amdgcn_readfirstlane(sMX[mi_]);                       \
    int my_ = __builtin_amdgcn_readfirstlane(sMY[mi_]);                       \
    int wdt_ = my_ & 4095;                                                    \
    int dd_ = (my_ >> 12) & 31;                                               \
    int v45_ = pw16 + ((my_ >> 17) & 63) - 32;                                \
    if (v45_ < 0) v45_ += NC45; else if (v45_ >= NC45) v45_ -= NC45;          \
    const unsigned short* ab_ = XT + (((size_t)(t + dd_ - WOFF) * NC45 + v45_) << 9); \
    A##S = *(const short8v*)(ab_ + laneA);                                    \
    const unsigned short* bb_ = PSIT + mx_ + kb2 * wdt_;                      \
    int bo_ = lconst + (((mx_ ^ lconst) & 1) ? (wdt_ - 1) : 0);               \
    B##S##0 = *(const short8v*)(bb_ + bo_);                                   \
    B##S##1 = *(const short8v*)(bb_ + 2 * wdt_ + bo_);                        \
    B##S##2 = *(const short8v*)(bb_ + 4 * wdt_ + bo_);                        \
    if (K4) { B##S##3 = *(const short8v*)(bb_ + 6 * wdt_ + bo_); } }

#define MFMAK(S, K4) {                                                        \
    acc0 = __builtin_amdgcn_mfma_f32_32x32x16_bf16(A##S, B##S##0, acc0, 0, 0, 0); \
    acc1 = __builtin_amdgcn_mfma_f32_32x32x16_bf16(A##S, B##S##1, acc1, 0, 0, 0); \
    acc2 = __builtin_amdgcn_mfma_f32_32x32x16_bf16(A##S, B##S##2, acc2, 0, 0, 0); \
    if (K4) { acc3 = __builtin_amdgcn_mfma_f32_32x32x16_bf16(A##S, B##S##3, acc3, 0, 0, 0); } }

#define HOTLOOP(K4)                                                           \
    LOADK(0, 0, K4) LOADK(1, 1, K4) LOADK(2, 2, K4) LOADK(3, 3, K4)           \
    {                                                                         \
      int iu = 0;                                                             \
      while (iu + 4 <= nU) {                                                  \
        MFMAK(0, K4) LOADK(0, iu + 4, K4)                                     \
        MFMAK(1, K4) LOADK(1, iu + 5, K4)                                     \
        MFMAK(2, K4) LOADK(2, iu + 6, K4)                                     \
        MFMAK(3, K4) LOADK(3, iu + 7, K4)                                     \
        iu += 4;                                                              \
      }                                                                       \
      if (iu < nU)     { MFMAK(0, K4) }                                       \
      if (iu + 1 < nU) { MFMAK(1, K4) }                                       \
      if (iu + 2 < nU) { MFMAK(2, K4) }                                       \
    }

// dump 32x32 acc (all 16 regs) for absolute k-basis KABS: c16 = 2*KABS + half
#define DUMPK(ACC, KABS) {                                                    \
    int b0_ = ((2 * (KABS)) << 9) + nn * 16 + 4 * g;                          \
    short4v q_;                                                               \
    q_[0]=(short)f2bf(ACC[0]);  q_[1]=(short)f2bf(ACC[1]);  q_[2]=(short)f2bf(ACC[2]);  q_[3]=(short)f2bf(ACC[3]);  \
    *(short4v*)(bp2w + b0_) = q_;                                             \
    q_[0]=(short)f2bf(ACC[4]);  q_[1]=(short)f2bf(ACC[5]);  q_[2]=(short)f2bf(ACC[6]);  q_[3]=(short)f2bf(ACC[7]);  \
    *(short4v*)(bp2w + b0_ + 8) = q_;                                         \
    q_[0]=(short)f2bf(ACC[8]);  q_[1]=(short)f2bf(ACC[9]);  q_[2]=(short)f2bf(ACC[10]); q_[3]=(short)f2bf(ACC[11]); \
    *(short4v*)(bp2w + b0_ + 512) = q_;                                       \
    q_[0]=(short)f2bf(ACC[12]); q_[1]=(short)f2bf(ACC[13]); q_[2]=(short)f2bf(ACC[14]); q_[3]=(short)f2bf(ACC[15]); \
    *(short4v*)(bp2w + b0_ + 512 + 8) = q_; }

__global__ __launch_bounds__(NTHR, 2) void disco_kernel(
    const unsigned short* __restrict__ XT, const unsigned short* __restrict__ PSIT,
    const unsigned short* __restrict__ w2g, const int* __restrict__ offsT,
    const int* __restrict__ wtab, float* __restrict__ y,
    int* __restrict__ counter) {
  const int tid = threadIdx.x;
  __shared__ __align__(16) unsigned short B2sh[4 * 7168];  // [pt][c16=14][512]
  __shared__ __align__(16) float Xch[4 * 1024];            // Dy cross-wave exchange
  __shared__ int Sbuf[362];
  __shared__ int sB[WLAT], sUc[WLAT + 1], sOff[WLAT], sW[WLAT];
  __shared__ int sMX[CT], sMY[CT];
  __shared__ int curItem;

  // ---- schedule (no trig: wtab precomputed) ----
  for (int j = tid; j < 361; j += NTHR) {
    int t0 = (j & 1) ? 360 - (j >> 1) : (j >> 1);   // poles first
    Sbuf[j] = 6 * ((wtab[t0] + CT - 1) / CT);
  }
  __syncthreads();
  if (tid == 0) {
    int run = 0;
    for (int j = 0; j < 361; ++j) { int v = Sbuf[j]; Sbuf[j] = run; run += v; }
    Sbuf[361] = run;
  }
  __syncthreads();
  const int NTOT = Sbuf[361];

  const int lane = tid & 63, wv = tid >> 6, nn = lane & 31, g = lane >> 5;
  const int g8 = g * 8;
  const int laneA = nn * 16 + g8;
  const int lconst = g8 - nn;
  const int ptl = wv & 3;     // ptile within pgroup
  const int kg = wv >> 2;     // 0: k 0..3   1: k 4..6
  const int kb2 = kg * 8;     // PSIT row offset (2*kbase)

  while (true) {
    if (tid == 0) curItem = atomicAdd(counter, 1);
    __syncthreads();   // also protects LDS tables from previous item's readers
    const int m = curItem;
    if (m >= NTOT) break;

    int lo = 0, hi = 360;
    while (lo < hi) {
      int mid = (lo + hi + 1) >> 1;
      if (Sbuf[mid] <= m) lo = mid; else hi = mid - 1;
    }
    const int j = lo;
    const int r = m - Sbuf[j];
    const int t = (j & 1) ? 360 - (j >> 1) : (j >> 1);
    const int pgroup = r % 6;
    const int part = r / 6;

    if (tid < WLAT) {
      int B = windowB(t, tid);
      sB[tid] = B;
      sOff[tid] = offsT[t * 21 + tid];
      sW[tid] = widthOf(B);
    }
    __syncthreads();
    if (tid == 0) {
      int run = 0; sUc[0] = 0;
      for (int d = 0; d < WLAT; ++d) {
        int B = sB[d];
        int np = (B >= 0) ? ((31 + B) >> 4) + ((B + 15) >> 4) + 1 : 0;
        run += np; sUc[d + 1] = run;
      }
    }
    __syncthreads();
    const int Wt = sUc[WLAT];
    int g0 = part * CT, g1 = g0 + CT;
    if (g1 > Wt) g1 = Wt;
    const int nU = g1 - g0;

    // flat per-unit metadata: PSIT base offset + {width, d, c} packed
    if (tid < nU) {
      int u = g0 + tid;
      int d = 0;
      while (sUc[d + 1] <= u) ++d;
      int B = sB[d];
      int bLo = (B >= 360) ? -360 : -B;
      int c = -((B + 15) >> 4) + (u - sUc[d]);
      sMX[tid] = sOff[d] + c * 16 - bLo + PAD_T;
      sMY[tid] = sW[d] | (d << 12) | ((c + 32) << 17);
    }
    __syncthreads();

    const int ptile = pgroup * 4 + ptl;   // 0..23 (23 = dead pad tile)
    const int pw = ptile * 32;
    const int pw16 = ptile * 2;

    f32x16 acc0, acc1, acc2, acc3;
#pragma unroll
    for (int z = 0; z < 16; ++z) { acc0[z] = 0; acc1[z] = 0; acc2[z] = 0; acc3[z] = 0; }

    short8v A0, A1, A2, A3;
    short8v B00, B01, B02, B03;
    short8v B10, B11, B12, B13;
    short8v B20, B21, B22, B23;
    short8v B30, B31, B32, B33;

    if (kg == 0) { HOTLOOP(1) } else { HOTLOOP(0) }

    // ---- dump G slices (packed b64 quads), then shared GEMM2 ----
    unsigned short* bp2w = B2sh + ptl * 7168;
    if (kg == 0) { DUMPK(acc0, 0) DUMPK(acc1, 1) DUMPK(acc2, 2) DUMPK(acc3, 3) }
    else         { DUMPK(acc0, 4) DUMPK(acc1, 5) DUMPK(acc2, 6) }
    __syncthreads();

    // GEMM2 half: kg0 contracts i 0..15 (even c16), kg1 contracts i 16..31 (odd)
    f32x16 Dy;
#pragma unroll
    for (int z = 0; z < 16; ++z) Dy[z] = 0.0f;
    {
      const unsigned short* bp2r = B2sh + ptl * 7168;
#pragma unroll
      for (int k2 = 0; k2 < 7; ++k2) {
        int c16 = 2 * k2 + kg;
        short8v wa = *(const short8v*)(w2g + ((c16 * 32 + nn) << 4) + g8);
        short8v gb = *(const short8v*)(bp2r + (c16 << 9) + (nn << 4) + g8);
        Dy = __builtin_amdgcn_mfma_f32_32x32x16_bf16(wa, gb, Dy, 0, 0, 0);
      }
    }

    // exchange partial Dy halves so atomic count stays 16/lane per ptile-pair
    float* xc = Xch + ptl * 1024;
    if (kg == 0) {
      f32x4 s0, s1;
      s0[0] = Dy[8];  s0[1] = Dy[9];  s0[2] = Dy[10]; s0[3] = Dy[11];
      s1[0] = Dy[12]; s1[1] = Dy[13]; s1[2] = Dy[14]; s1[3] = Dy[15];
      *(f32x4*)(xc + 512 + lane * 8) = s0;
      *(f32x4*)(xc + 512 + lane * 8 + 4) = s1;
    } else {
      f32x4 s0, s1;
      s0[0] = Dy[0]; s0[1] = Dy[1]; s0[2] = Dy[2]; s0[3] = Dy[3];
      s1[0] = Dy[4]; s1[1] = Dy[5]; s1[2] = Dy[6]; s1[3] = Dy[7];
      *(f32x4*)(xc + lane * 8) = s0;
      *(f32x4*)(xc + lane * 8 + 4) = s1;
    }
    __syncthreads();
    const int p = pw + nn;
    if (kg == 0) {
      f32x4 u0 = *(const f32x4*)(xc + lane * 8);
      f32x4 u1 = *(const f32x4*)(xc + lane * 8 + 4);
      if (p < NLON_O) {
#pragma unroll
        for (int rr = 0; rr < 4; ++rr) {
          int o = rr + 4 * g;
          atomicAdd(&y[((size_t)o * NLAT_O + t) * NLON_O + p], Dy[rr] + u0[rr]);
        }
#pragma unroll
        for (int rr = 4; rr < 8; ++rr) {
          int o = (rr & 3) + 8 + 4 * g;
          atomicAdd(&y[((size_t)o * NLAT_O + t) * NLON_O + p], Dy[rr] + u1[rr - 4]);
        }
      }
    } else {
      f32x4 u0 = *(const f32x4*)(xc + 512 + lane * 8);
      f32x4 u1 = *(const f32x4*)(xc + 512 + lane * 8 + 4);
      if (p < NLON_O) {
#pragma unroll
        for (int rr = 8; rr < 12; ++rr) {
          int o = (rr & 3) + 16 + 4 * g;
          atomicAdd(&y[((size_t)o * NLAT_O + t) * NLON_O + p], Dy[rr] + u0[rr - 8]);
        }
#pragma unroll
        for (int rr = 12; rr < 16; ++rr) {
          int o = (rr & 3) + 24 + 4 * g;
          atomicAdd(&y[((size_t)o * NLAT_O + t) * NLON_O + p], Dy[rr] + u1[rr - 12]);
        }
      }
    }
  }
}

// ---------------- launch ----------------------------------------------------
extern "C" void kernel_launch(void* const* d_in, const int* in_sizes, int n_in,
                              void* d_out, int out_size, void* d_ws, size_t ws_size,
                              hipStream_t stream) {
  (void)in_sizes; (void)n_in; (void)out_size; (void)ws_size;
  const float* x = (const float*)d_in[0];
  const float* w = (const float*)d_in[1];
  float* y = (float*)d_out;

  // ws: XT (16.6MB) | PSIF f32 (24MB cap) | PSIT bf16 (52MB cap) | small tables
  unsigned short* XT = (unsigned short*)d_ws;                 // 8,317,440 shorts
  float* PSIF = (float*)(XT + (size_t)NLAT_O * NC45 * 512);   // cap 6e6 f32
  unsigned short* PSIT = (unsigned short*)(PSIF + 6000000);   // cap 26e6 shorts
  unsigned short* w2 = PSIT + 26000000;                       // 7168
  float* sums = (float*)(w2 + 7168);                          // 2527
  int* offsF = (int*)(sums + NLAT_O * K_N);                   // NE+1
  int* offsT = offsF + NE + 1;                                // NE+1
  int* wtab = offsT + NE + 1;                                 // 361
  int* counter = wtab + 361;                                  // 1

  hipMemsetAsync(y, 0, (size_t)CO_N * NLAT_O * NLON_O * sizeof(float), stream);

  prep_kernel<<<1, 256, 0, stream>>>(w, w2, offsF, offsT, wtab, sums, counter);
  int n_up = NLAT_O * NC45 * 512;
  upsample_kernel<<<(n_up + 255) / 256, 256, 0, stream>>>(x, XT);
  psi_raw_kernel<<<dim3(NLAT_O, WLAT), 256, 0, stream>>>(offsF, PSIF, sums);
  psi_toep_kernel<<<dim3(NLAT_O, WLAT), 256, 0, stream>>>(offsF, offsT, PSIF, sums, PSIT);
  disco_kernel<<<NBLK, NTHR, 0, stream>>>(XT, PSIT, w2, offsT, wtab, y, counter);
}

// Round 2
// 522.895 us; speedup vs baseline: 1.2511x; 1.2511x over previous
//
#include <hip/hip_runtime.h>
#include <hip/hip_bf16.h>
#include <math.h>

#define NLAT_I 240
#define NLON_I 480
#define NLAT_O 361
#define NLON_O 720
#define CI_N 32
#define CO_N 32
#define K_N 7
#define WOFF 10
#define WLAT 21

#define PI_F 3.14159265358979323846f
#define TWOPI_F 6.28318530717958647692f
#define DLAT_V (PI_F / 360.0f)
#define DPHI_V (TWOPI_F / 720.0f)
#define CUTOFF_V (3.25f * PI_F / 120.0f)
#define DR_V (CUTOFF_V / 3.0f)
#define IDR_V (1.0f / DR_V)
#define DPH_V (TWOPI_F / 3.0f)
#define IDPH_V (1.0f / DPH_V)
#define QF_V (DLAT_V * DPHI_V)

#define PAD_T 64        // Toeplitz pad (covers fragment reach beyond support)
#define CT 64           // positions per work item
#define NBLK 512
#define NC45 45         // 720/16 column chunks
#define NE 7581         // 361*21

typedef __attribute__((ext_vector_type(8))) short short8v;
typedef __attribute__((ext_vector_type(4))) short short4v;
typedef __attribute__((ext_vector_type(16))) float f32x16;

__device__ __forceinline__ unsigned short f2bf(float f) {
  __hip_bfloat16 h = __float2bfloat16(f);   // RTNE
  union { __hip_bfloat16 b; unsigned short s; } u; u.b = h; return u.s;
}

// ---------------- psi evaluation --------------------------------------------
__device__ __forceinline__ void psi_eval(float ct, float st, float cg, float sg,
                                         float q, float bang, float v[7]) {
  float sb, cb;
  sincosf(bang, &sb, &cb);
  float dx = sg * cb - st;
  float dy = sg * sb;
  float dz = cg - ct;
  float c2 = dx * dx + dy * dy + dz * dz;
  float r = 2.0f * asinf(fminf(1.0f, 0.5f * sqrtf(c2)));
  if (r <= CUTOFF_V) {
    float xx = ct * cb * sg - st * cg;
    float yy = sb * sg;
    float phi = atan2f(yy, xx);
    if (phi < 0.0f) phi += TWOPI_F;
    v[0] = fmaxf(0.0f, 1.0f - r * IDR_V) * q;
#pragma unroll
    for (int k = 1; k < 7; ++k) {
      const float irdr = (float)(1 + (k - 1) / 3) * DR_V;
      const float ipph = (float)((k - 1) % 3) * DPH_V;
      float rad = fmaxf(0.0f, 1.0f - fabsf(r - irdr) * IDR_V);
      float dd = fabsf(phi - ipph);
      dd = fminf(dd, TWOPI_F - dd);
      float az = fmaxf(0.0f, 1.0f - dd * IDPH_V);
      v[k] = rad * az * q;
    }
  } else {
#pragma unroll
    for (int k = 0; k < 7; ++k) v[k] = 0.0f;
  }
}

// per-(t,d) lon window half-width: -1 empty, 360 full circle
__device__ __forceinline__ int windowB(int t, int d) {
  int tp = t + d - WOFF;
  if (tp < 0 || tp > NLAT_O - 1) return -1;
  float th = (float)t * DLAT_V, ga = (float)tp * DLAT_V;
  float st = sinf(th), ct = cosf(th), sg = sinf(ga), cg = cosf(ga);
  float den = st * sg;
  float num = cosf(CUTOFF_V) - ct * cg;
  if (den < 1e-9f) return (fabsf(th - ga) <= CUTOFF_V) ? 360 : -1;
  if (num >= den) return -1;
  if (num <= -den) return 360;
  int B = (int)ceilf(acosf(num / den) * (1.0f / DPHI_V)) + 1;  // +1 margin; psi masks
  return B > 360 ? 360 : B;
}

__device__ __forceinline__ int nsupOf(int B) { return (B >= 360) ? 720 : 2 * B + 1; }
__device__ __forceinline__ int widthOf(int B) {
  return (B < 0) ? 0 : ((nsupOf(B) + 129) & ~1);   // even
}

// ---------------- kernel 0: prep (w2, scans, tables, counters) --------------
__global__ void prep_kernel(const float* __restrict__ w, unsigned short* __restrict__ w2,
                            int* __restrict__ offsF, int* __restrict__ offsT,
                            int* __restrict__ wtab, float* __restrict__ sums,
                            int* __restrict__ counter, int* __restrict__ gB,
                            int* __restrict__ gUc) {
  const int tid = threadIdx.x;
  __shared__ int temp[256];
  if (tid < 8) counter[tid] = 0;
  for (int idx = tid; idx < 361 * 7; idx += 256) sums[idx] = 0.0f;
  // w2[c16][o][kk] = bf16(w[o][i][k]) with ci=c16*16+kk, k=ci>>5, i=ci&31
  for (int idx = tid; idx < 14 * 32 * 16; idx += 256) {
    int kk = idx & 15; int o = (idx >> 4) & 31; int c16 = idx >> 9;
    int ci = c16 * 16 + kk; int i = ci & 31; int k = ci >> 5;
    w2[idx] = f2bf(w[(o * 32 + i) * 7 + k]);
  }
  for (int e = tid; e < NE; e += 256) {
    int t = e / 21, d = e % 21;
    int B = windowB(t, d);
    gB[e] = B;
    offsF[e] = (B >= 0) ? nsupOf(B) * 7 : 0;
    offsT[e] = 14 * widthOf(B);
  }
  __syncthreads();
  for (int t = tid; t < 361; t += 256) {
    int run = 0;
    for (int d = 0; d < WLAT; ++d) {
      gUc[t * 22 + d] = run;
      int B = gB[t * 21 + d];
      int np = (B >= 0) ? ((31 + B) >> 4) + ((B + 15) >> 4) + 1 : 0;
      run += np;
    }
    gUc[t * 22 + 21] = run;
    wtab[t] = run;
  }
  __syncthreads();
  // two-level exclusive scan for offsF then offsT (chunk = 30, 256*30 >= NE)
#pragma unroll 1
  for (int pass = 0; pass < 2; ++pass) {
    int* a = pass ? offsT : offsF;
    int s = tid * 30, e = s + 30; if (e > NE) e = NE; if (s > NE) s = NE;
    int sum = 0;
    for (int i = s; i < e; ++i) sum += a[i];
    temp[tid] = sum;
    __syncthreads();
    if (tid == 0) {
      int run = 0;
      for (int i = 0; i < 256; ++i) { int v = temp[i]; temp[i] = run; run += v; }
      a[NE] = run;
    }
    __syncthreads();
    int run = temp[tid];
    for (int i = s; i < e; ++i) { int v = a[i]; a[i] = run; run += v; }
    __syncthreads();
  }
}

// ---------------- kernel 1: bilinear upsample -> tiled bf16 XT --------------
// XT[t][c][i][kk] with b = c*16+kk  (wave A-load = contiguous 1KB)
__global__ void upsample_kernel(const float* __restrict__ x,
                                unsigned short* __restrict__ XT) {
  int idx = blockIdx.x * 256 + threadIdx.x;
  if (idx >= NLAT_O * NC45 * 512) return;
  int kk = idx & 15;
  int i = (idx >> 4) & 31;
  int c = (idx >> 9) % NC45;
  int t = idx / (NC45 * 512);
  int p = c * 16 + kk;

  double post = (double)t * (239.0 / 360.0);
  int i0 = (int)floor(post);
  if (i0 < 0) i0 = 0;
  if (i0 > NLAT_I - 1) i0 = NLAT_I - 1;
  int i1 = i0 + 1; if (i1 > NLAT_I - 1) i1 = NLAT_I - 1;
  float wt = (float)(post - (double)i0);

  double posp = (double)p * (2.0 / 3.0);
  double j0f = floor(posp);
  int j0 = ((int)j0f) % NLON_I;
  int j1 = (j0 + 1) % NLON_I;
  float wp = (float)(posp - j0f);

  const float* xi = x + (size_t)i * (NLAT_I * NLON_I);
  float a = xi[i0 * NLON_I + j0];
  float b = xi[i0 * NLON_I + j1];
  float cc = xi[i1 * NLON_I + j0];
  float d = xi[i1 * NLON_I + j1];
  float l0 = (1.0f - wt) * a + wt * cc;
  float l1 = (1.0f - wt) * b + wt * d;
  XT[idx] = f2bf((1.0f - wp) * l0 + wp * l1);
}

// ---------------- kernel 2: raw psi (f32) + fused per-(k,t) partial sums ----
__global__ void psi_raw_kernel(const int* __restrict__ offsF,
                               float* __restrict__ PSIF,
                               float* __restrict__ sums) {
  int t = blockIdx.x, d = blockIdx.y;
  int B = windowB(t, d);
  if (B < 0) return;
  int nsup = nsupOf(B);
  int bLo = (B >= 360) ? -360 : -B;
  int offF = offsF[t * 21 + d];
  int tp = t + d - WOFF;
  float th = (float)t * DLAT_V, ga = (float)tp * DLAT_V;
  float st, ct, sg, cg;
  sincosf(th, &st, &ct);
  sincosf(ga, &sg, &cg);
  float q = sg * QF_V;
  float acc[7];
#pragma unroll
  for (int k = 0; k < 7; ++k) acc[k] = 0.0f;
  for (int ix = threadIdx.x; ix < nsup; ix += 256) {
    float v[7];
    psi_eval(ct, st, cg, sg, q, (float)(bLo + ix) * DPHI_V, v);
#pragma unroll
    for (int k = 0; k < 7; ++k) { PSIF[offF + k * nsup + ix] = v[k]; acc[k] += v[k]; }
  }
#pragma unroll
  for (int k = 0; k < 7; ++k) {
    float a = acc[k];
    for (int off = 32; off > 0; off >>= 1) a += __shfl_down(a, off, 64);
    acc[k] = a;
  }
  __shared__ float red[4][7];
  int wid = threadIdx.x >> 6;
  if ((threadIdx.x & 63) == 0) {
#pragma unroll
    for (int k = 0; k < 7; ++k) red[wid][k] = acc[k];
  }
  __syncthreads();
  if (threadIdx.x == 0) {
#pragma unroll
    for (int k = 0; k < 7; ++k)
      atomicAdd(&sums[t * 7 + k], red[0][k] + red[1][k] + red[2][k] + red[3][k]);
  }
}

// ---------------- kernel 3: normalized bf16 Toeplitz (2 parity copies) ------
__global__ void psi_toep_kernel(const int* __restrict__ offsF,
                                const int* __restrict__ offsT,
                                const float* __restrict__ PSIF,
                                const float* __restrict__ sums,
                                unsigned short* __restrict__ PSIT) {
  int t = blockIdx.x, d = blockIdx.y;
  int B = windowB(t, d);
  if (B < 0) return;
  int nsup = nsupOf(B);
  int width = widthOf(B);
  int offF = offsF[t * 21 + d];
  int offT = offsT[t * 21 + d];
  float rc[7];
#pragma unroll
  for (int k = 0; k < 7; ++k) rc[k] = 1.0f / fmaxf(sums[t * 7 + k], 1e-8f);
  for (int ix = threadIdx.x; ix <= width; ix += 256) {
    int isup = ix - PAD_T;
    unsigned short vv[7];
    if (isup >= 0 && isup < nsup) {
#pragma unroll
      for (int k = 0; k < 7; ++k)
        vv[k] = f2bf(PSIF[offF + k * nsup + isup] * rc[k]);
    } else {
#pragma unroll
      for (int k = 0; k < 7; ++k) vv[k] = 0;
    }
    if (ix < width) {
#pragma unroll
      for (int k = 0; k < 7; ++k) PSIT[offT + (2 * k) * width + ix] = vv[k];
    }
    if (ix >= 1) {
#pragma unroll
      for (int k = 0; k < 7; ++k) PSIT[offT + (2 * k + 1) * width + ix - 1] = vv[k];
    }
  }
}

// ---------------- kernel 4: persistent pipelined MFMA conv + channel MFMA ---
// Round-0 structure (4 waves, 7-acc, 2-stage pipeline) + XCD-chunked stealing
// scheduler (PSIT slice per XCD stays L2-resident) + precomputed window tables
// (no trig / serial scan per item) + packed b64 LDS dumps.

#define LOADSET(S, CC) {                                                  \
    int v45 = pw16 + (CC);                                                \
    if (v45 < 0) v45 += NC45;                                             \
    if (v45 >= NC45) v45 -= NC45;                                         \
    A##S = *(const short8v*)(XT + (((size_t)tpd * NC45 + v45) << 9) + laneA); \
    int jbIdx = (CC) * 16 + lconst - bLo + PAD_T;                         \
    const unsigned short* bp = pbase + jbIdx + ((jbIdx & 1) ? (wdt - 1) : 0); \
    B##S##0 = *(const short8v*)(bp);                                      \
    B##S##1 = *(const short8v*)(bp + ks);                                 \
    B##S##2 = *(const short8v*)(bp + 2 * ks);                             \
    B##S##3 = *(const short8v*)(bp + 3 * ks);                             \
    B##S##4 = *(const short8v*)(bp + 4 * ks);                             \
    B##S##5 = *(const short8v*)(bp + 5 * ks);                             \
    B##S##6 = *(const short8v*)(bp + 6 * ks); }

#define MFMASET(S) {                                                      \
    acc0 = __builtin_amdgcn_mfma_f32_32x32x16_bf16(A##S, B##S##0, acc0, 0, 0, 0); \
    acc1 = __builtin_amdgcn_mfma_f32_32x32x16_bf16(A##S, B##S##1, acc1, 0, 0, 0); \
    acc2 = __builtin_amdgcn_mfma_f32_32x32x16_bf16(A##S, B##S##2, acc2, 0, 0, 0); \
    acc3 = __builtin_amdgcn_mfma_f32_32x32x16_bf16(A##S, B##S##3, acc3, 0, 0, 0); \
    acc4 = __builtin_amdgcn_mfma_f32_32x32x16_bf16(A##S, B##S##4, acc4, 0, 0, 0); \
    acc5 = __builtin_amdgcn_mfma_f32_32x32x16_bf16(A##S, B##S##5, acc5, 0, 0, 0); \
    acc6 = __builtin_amdgcn_mfma_f32_32x32x16_bf16(A##S, B##S##6, acc6, 0, 0, 0); }

// packed dump: half HB of ACC (regs 8*HB..8*HB+7) into b2 rows for k-basis KK
#define DUMP2(ACC, KK, HB) {                                              \
    short4v q_;                                                           \
    q_[0]=(short)f2bf(ACC[8*(HB)+0]); q_[1]=(short)f2bf(ACC[8*(HB)+1]);   \
    q_[2]=(short)f2bf(ACC[8*(HB)+2]); q_[3]=(short)f2bf(ACC[8*(HB)+3]);   \
    *(short4v*)(b2 + ((KK) << 9) + b0_) = q_;                             \
    q_[0]=(short)f2bf(ACC[8*(HB)+4]); q_[1]=(short)f2bf(ACC[8*(HB)+5]);   \
    q_[2]=(short)f2bf(ACC[8*(HB)+6]); q_[3]=(short)f2bf(ACC[8*(HB)+7]);   \
    *(short4v*)(b2 + ((KK) << 9) + b0_ + 8) = q_; }

__global__ __launch_bounds__(256, 2) void disco_kernel(
    const unsigned short* __restrict__ XT, const unsigned short* __restrict__ PSIT,
    const unsigned short* __restrict__ w2g, const int* __restrict__ offsT,
    const int* __restrict__ wtab, const int* __restrict__ gB,
    const int* __restrict__ gUc, float* __restrict__ y,
    int* __restrict__ counter) {
  const int tid = threadIdx.x;
  __shared__ __align__(16) unsigned short b2all[4 * 3584];
  __shared__ int Sbuf[362];
  __shared__ int sB[WLAT], sUc[WLAT + 1], sOff[WLAT], sW[WLAT];
  __shared__ int curItem, sSv;

  // ---- schedule (no trig: wtab precomputed) ----
  for (int j = tid; j < 361; j += 256) {
    int t = (j & 1) ? 360 - (j >> 1) : (j >> 1);   // poles first
    Sbuf[j] = 6 * ((wtab[t] + CT - 1) / CT);
  }
  __syncthreads();
  if (tid == 0) {
    int run = 0;
    for (int j = 0; j < 361; ++j) { int v = Sbuf[j]; Sbuf[j] = run; run += v; }
    Sbuf[361] = run;
    sSv = 0;
  }
  __syncthreads();
  const int NTOT = Sbuf[361];
  const int xcd = blockIdx.x & 7;

  const int lane = tid & 63, wv = tid >> 6, nn = lane & 31, g = lane >> 5;
  const int g8 = g * 8;
  const int laneA = nn * 16 + g8;
  const int lconst = g8 - nn;

  while (true) {
    // XCD-chunked dynamic scheduling: own chunk first, steal when exhausted.
    if (tid == 0) {
      int mm = NTOT;
      int s2 = sSv;
      while (s2 < 8) {
        int cx = (xcd + s2) & 7;
        int b0 = (NTOT * cx) >> 3;
        int b1 = (NTOT * (cx + 1)) >> 3;
        int off = atomicAdd(&counter[cx], 1);
        if (b0 + off < b1) { mm = b0 + off; break; }
        ++s2;
      }
      sSv = s2;
      curItem = mm;
    }
    __syncthreads();   // also protects sB/sUc from previous item's readers
    const int m = curItem;
    if (m >= NTOT) break;

    int lo = 0, hi = 360;
    while (lo < hi) {
      int mid = (lo + hi + 1) >> 1;
      if (Sbuf[mid] <= m) lo = mid; else hi = mid - 1;
    }
    const int j = lo;
    const int r = m - Sbuf[j];
    const int t = (j & 1) ? 360 - (j >> 1) : (j >> 1);
    const int pgroup = r % 6;
    const int part = r / 6;

    if (tid < WLAT) {
      int B = gB[t * 21 + tid];
      sB[tid] = B;
      sOff[tid] = offsT[t * 21 + tid];
      sW[tid] = widthOf(B);
    }
    if (tid < WLAT + 1) sUc[tid] = gUc[t * 22 + tid];
    __syncthreads();

    const int Wt = sUc[WLAT];
    int g0 = part * CT, g1 = g0 + CT;
    if (g1 > Wt) g1 = Wt;

    const int ptile = pgroup * 4 + wv;   // 0..23 (23 = dead pad tile)
    const int pw = ptile * 32;
    const int pw16 = ptile * 2;

    f32x16 acc0, acc1, acc2, acc3, acc4, acc5, acc6;
#pragma unroll
    for (int z = 0; z < 16; ++z) {
      acc0[z]=0; acc1[z]=0; acc2[z]=0; acc3[z]=0; acc4[z]=0; acc5[z]=0; acc6[z]=0;
    }

    // ---- hot loop: d-runs with 2-stage software pipeline ----
    short8v A0, A1;
    short8v B00, B01, B02, B03, B04, B05, B06;
    short8v B10, B11, B12, B13, B14, B15, B16;

    int gi = g0;
    int d = 0;
    while (d < WLAT && sUc[d + 1] <= gi) ++d;
    while (gi < g1) {
      const int B = sB[d];
      const int bLo = (B >= 360) ? -360 : -B;
      const int cmin = -((B + 15) >> 4);
      const int tpd = t + d - WOFF;
      const int wdt = sW[d];
      const int ks = 2 * wdt;
      const unsigned short* pbase = PSIT + sOff[d];
      const int rend = sUc[d + 1];
      const int gend = (rend < g1) ? rend : g1;
      const int n = gend - gi;
      int c = cmin + (gi - sUc[d]);

      LOADSET(0, c)
      int it = 0;
      for (; it + 2 <= n; it += 2) {
        LOADSET(1, c + 1)
        MFMASET(0)
        if (it + 2 < n) { LOADSET(0, c + 2) }
        MFMASET(1)
        c += 2;
      }
      if (it < n) { MFMASET(0) }

      gi = gend;
      ++d;
      while (d < WLAT && sUc[d + 1] <= gi) ++d;
    }

    // ---- GEMM2: y[o,p] = sum_{ci=(k,i)} w2[o,ci] * G[ci,p] (wave-private) --
    unsigned short* b2 = b2all + wv * 3584;
    const int b0_ = nn * 16 + 4 * g;
    f32x16 Dy;
#pragma unroll
    for (int z = 0; z < 16; ++z) Dy[z] = 0.0f;

    {  // half 0: i in [0,16) <-> regs 0..7
      DUMP2(acc0, 0, 0) DUMP2(acc1, 1, 0) DUMP2(acc2, 2, 0) DUMP2(acc3, 3, 0)
      DUMP2(acc4, 4, 0) DUMP2(acc5, 5, 0) DUMP2(acc6, 6, 0)
#pragma unroll
      for (int k2 = 0; k2 < 7; ++k2) {
        short8v A2 = *(const short8v*)(w2g + (((2 * k2 + 0) * 32 + nn) << 4) + g8);
        short8v B2f = *(const short8v*)(b2 + (k2 << 9) + (nn << 4) + g8);
        Dy = __builtin_amdgcn_mfma_f32_32x32x16_bf16(A2, B2f, Dy, 0, 0, 0);
      }
    }
    {  // half 1: i in [16,32) <-> regs 8..15
      DUMP2(acc0, 0, 1) DUMP2(acc1, 1, 1) DUMP2(acc2, 2, 1) DUMP2(acc3, 3, 1)
      DUMP2(acc4, 4, 1) DUMP2(acc5, 5, 1) DUMP2(acc6, 6, 1)
#pragma unroll
      for (int k2 = 0; k2 < 7; ++k2) {
        short8v A2 = *(const short8v*)(w2g + (((2 * k2 + 1) * 32 + nn) << 4) + g8);
        short8v B2f = *(const short8v*)(b2 + (k2 << 9) + (nn << 4) + g8);
        Dy = __builtin_amdgcn_mfma_f32_32x32x16_bf16(A2, B2f, Dy, 0, 0, 0);
      }
    }

    const int p = pw + nn;
    if (p < NLON_O) {
#pragma unroll
      for (int rr = 0; rr < 16; ++rr) {
        int o = (rr & 3) + 8 * (rr >> 2) + 4 * g;
        atomicAdd(&y[((size_t)o * NLAT_O + t) * NLON_O + p], Dy[rr]);
      }
    }
  }
}

// ---------------- launch ----------------------------------------------------
extern "C" void kernel_launch(void* const* d_in, const int* in_sizes, int n_in,
                              void* d_out, int out_size, void* d_ws, size_t ws_size,
                              hipStream_t stream) {
  (void)in_sizes; (void)n_in; (void)out_size; (void)ws_size;
  const float* x = (const float*)d_in[0];
  const float* w = (const float*)d_in[1];
  float* y = (float*)d_out;

  // ws: XT (16.6MB) | PSIF f32 (24MB cap) | PSIT bf16 (52MB cap) | small tables
  unsigned short* XT = (unsigned short*)d_ws;                 // 8,317,440 shorts
  float* PSIF = (float*)(XT + (size_t)NLAT_O * NC45 * 512);   // cap 6e6 f32
  unsigned short* PSIT = (unsigned short*)(PSIF + 6000000);   // cap 26e6 shorts
  unsigned short* w2 = PSIT + 26000000;                       // 7168
  float* sums = (float*)(w2 + 7168);                          // 2527
  int* offsF = (int*)(sums + NLAT_O * K_N);                   // NE+1
  int* offsT = offsF + NE + 1;                                // NE+1
  int* wtab = offsT + NE + 1;                                 // 361
  int* counter = wtab + 361;                                  // 8
  int* gB = counter + 8;                                      // NE
  int* gUc = gB + NE;                                         // 361*22

  hipMemsetAsync(y, 0, (size_t)CO_N * NLAT_O * NLON_O * sizeof(float), stream);

  prep_kernel<<<1, 256, 0, stream>>>(w, w2, offsF, offsT, wtab, sums, counter, gB, gUc);
  int n_up = NLAT_O * NC45 * 512;
  upsample_kernel<<<(n_up + 255) / 256, 256, 0, stream>>>(x, XT);
  psi_raw_kernel<<<dim3(NLAT_O, WLAT), 256, 0, stream>>>(offsF, PSIF, sums);
  psi_toep_kernel<<<dim3(NLAT_O, WLAT), 256, 0, stream>>>(offsF, offsT, PSIF, sums, PSIT);
  disco_kernel<<<NBLK, 256, 0, stream>>>(XT, PSIT, w2, offsT, wtab, gB, gUc, y, counter);
}